// Round 12
// baseline (950.464 us; speedup 1.0000x reference)
//
#include <hip/hip_runtime.h>

#define NN 100000
#define EE 1600000
#define FIN 512
#define HID 64
#define NC 16
#define CPAD 16          // one bucket cursor per 64B line

#define KB2 391          // buckets: 256 dst nodes each, ceil(100000/256)
#define BCAP2 4608       // staged entries per bucket (mean 4096, +8 sigma)
#define S1E 2048         // edges per bin block
#define NBIN ((EE + S1E - 1) / S1E)

typedef __attribute__((ext_vector_type(8))) short bf16x8;
typedef __attribute__((ext_vector_type(4))) float f32x4;

__device__ __forceinline__ unsigned short f2bf(float f) {
    union { float f; unsigned u; } v; v.f = f;
    unsigned r = v.u + 0x7FFFu + ((v.u >> 16) & 1u);   // RNE
    return (unsigned short)(r >> 16);
}
__device__ __forceinline__ float asf(unsigned u) {
    union { unsigned u; float f; } v; v.u = u; return v.f;
}
__device__ __forceinline__ float bf2f(unsigned short h) {
    union { unsigned u; float f; } v; v.u = ((unsigned)h) << 16;
    return v.f;
}

// ---------------- init: zero bucket cursors + W1 -> bf16 transposed [col][k] ----------------
__global__ void k_init(const float* __restrict__ W1, unsigned short* __restrict__ W1t,
                       unsigned* __restrict__ gcur) {
    int id = blockIdx.x * blockDim.x + threadIdx.x;
    if (id < KB2 * CPAD) gcur[id] = 0u;
    if (id < HID * FIN) {
        int c = id >> 9;
        int k = id & 511;
        W1t[id] = f2bf(W1[(size_t)k * HID + c]);
    }
}

// ---------------- bin (R9, proven): bucket edges by dst, coalesced staged output ----------------
__global__ __launch_bounds__(256) void k_bin(
    const int* __restrict__ erow, const int* __restrict__ ecol,
    unsigned* __restrict__ gcur, unsigned* __restrict__ staged) {
    __shared__ unsigned hist[512];
    __shared__ unsigned scanb[512];
    __shared__ unsigned cur[512];
    __shared__ unsigned sbase[512];
    __shared__ unsigned pk[S1E];
    __shared__ unsigned ga[S1E];
    const int t = threadIdx.x;
    const int e0 = blockIdx.x * S1E;

    hist[t] = 0; hist[t + 256] = 0;
    cur[t] = 0;  cur[t + 256] = 0;
    __syncthreads();

    unsigned pkd[8];
    int bs[8];
#pragma unroll
    for (int i = 0; i < 8; ++i) {
        int e = e0 + i * 256 + t;
        if (e < EE) {
            int c = ecol[e];
            int src = erow[e];
            int b = c >> 8;
            bs[i] = b;
            pkd[i] = (unsigned)src | ((unsigned)(c & 255) << 17);
            atomicAdd(&hist[b], 1u);
        } else {
            bs[i] = -1;
        }
    }
    __syncthreads();
    scanb[t] = hist[t];
    scanb[t + 256] = hist[t + 256];
    __syncthreads();
    for (int d = 1; d < 256; d <<= 1) {
        unsigned aA = (t >= d) ? scanb[t - d] : 0u;
        unsigned aB = (t >= d) ? scanb[256 + t - d] : 0u;
        __syncthreads();
        scanb[t] += aA;
        scanb[256 + t] += aB;
        __syncthreads();
    }
    unsigned totA = scanb[255];
    scanb[256 + t] += totA;
    __syncthreads();
    if (hist[t] > 0) sbase[t] = atomicAdd(&gcur[(size_t)t * CPAD], hist[t]);
    {
        int t2 = t + 256;
        if (t2 < KB2 && hist[t2] > 0) sbase[t2] = atomicAdd(&gcur[(size_t)t2 * CPAD], hist[t2]);
    }
    __syncthreads();
#pragma unroll
    for (int i = 0; i < 8; ++i) {
        int b = bs[i];
        if (b >= 0) {
            unsigned ls = atomicAdd(&cur[b], 1u);
            unsigned pos = scanb[b] - hist[b] + ls;
            unsigned gp = sbase[b] + ls;
            pk[pos] = pkd[i];
            ga[pos] = (gp < BCAP2) ? ((unsigned)b * BCAP2 + gp) : 0xFFFFFFFFu;
        }
    }
    __syncthreads();
    unsigned tot = scanb[511];
#pragma unroll
    for (int i = 0; i < 8; ++i) {
        unsigned idx = i * 256 + t;
        if (idx < tot && ga[idx] != 0xFFFFFFFFu) staged[ga[idx]] = pk[idx];
    }
}

// ---------------- cnt: per-bucket degree count -> dinv (needed by gemm1 prefold) ----------------
__global__ __launch_bounds__(256) void k_cnt(
    const unsigned* __restrict__ gcur, const unsigned* __restrict__ staged,
    float* __restrict__ dinv) {
    __shared__ unsigned lc[256];
    const int t = threadIdx.x;
    const int b = blockIdx.x;
    lc[t] = 0;
    __syncthreads();
    unsigned n = gcur[(size_t)b * CPAD];
    if (n > BCAP2) n = BCAP2;
    const unsigned base = (unsigned)b * BCAP2;
    for (unsigned i = t; i < n; i += 256) atomicAdd(&lc[staged[base + i] >> 17], 1u);
    __syncthreads();
    int node = (b << 8) + t;
    if (node < NN) dinv[node] = 1.0f / sqrtf((float)(lc[t] + 1u));   // +1 self-loop
}

// ---------------- layer 1 GEMM via MFMA: h1s = bf16( (A@W1) * dinv ) ----------------
#define BM 128
#define BK 64

__global__ __launch_bounds__(256) void k_gemm1(
    const float* __restrict__ A, const unsigned short* __restrict__ W1t,
    const float* __restrict__ dinv, unsigned short* __restrict__ h1s) {
    __shared__ unsigned short sA[BM * BK];
    __shared__ unsigned short sB[HID * BK];
    const int t = threadIdx.x;
    const int w = t >> 6;
    const int l = t & 63;
    const int row0 = blockIdx.x * BM;

    f32x4 acc[2][4];
#pragma unroll
    for (int fr = 0; fr < 2; ++fr)
#pragma unroll
        for (int fc = 0; fc < 4; ++fc)
            acc[fr][fc] = (f32x4){0.f, 0.f, 0.f, 0.f};

    for (int kb = 0; kb < FIN; kb += BK) {
        __syncthreads();
#pragma unroll
        for (int i = 0; i < 4; ++i) {
            int idx = i * 256 + t;
            int r = idx >> 3, g = idx & 7;
            float4 v0 = {0.f, 0.f, 0.f, 0.f}, v1 = {0.f, 0.f, 0.f, 0.f};
            if (row0 + r < NN) {
                const float* p = &A[(size_t)(row0 + r) * FIN + kb + g * 8];
                v0 = *reinterpret_cast<const float4*>(p);
                v1 = *reinterpret_cast<const float4*>(p + 4);
            }
            unsigned short tmp[8] = {f2bf(v0.x), f2bf(v0.y), f2bf(v0.z), f2bf(v0.w),
                                     f2bf(v1.x), f2bf(v1.y), f2bf(v1.z), f2bf(v1.w)};
            *reinterpret_cast<uint4*>((char*)sA + r * 128 + ((g ^ (r & 7)) << 4)) =
                *reinterpret_cast<uint4*>(tmp);
        }
#pragma unroll
        for (int i = 0; i < 2; ++i) {
            int idx = i * 256 + t;
            int c = idx >> 3, g = idx & 7;
            uint4 v = *reinterpret_cast<const uint4*>(&W1t[(size_t)c * FIN + kb + g * 8]);
            *reinterpret_cast<uint4*>((char*)sB + c * 128 + ((g ^ (c & 7)) << 4)) = v;
        }
        __syncthreads();
#pragma unroll
        for (int ks = 0; ks < 2; ++ks) {
            const int gk = ks * 4 + (l >> 4);
            bf16x8 a[2], b[4];
#pragma unroll
            for (int fr = 0; fr < 2; ++fr) {
                int r = w * 32 + fr * 16 + (l & 15);
                a[fr] = *reinterpret_cast<const bf16x8*>((char*)sA + r * 128 + ((gk ^ (r & 7)) << 4));
            }
#pragma unroll
            for (int fc = 0; fc < 4; ++fc) {
                int c = fc * 16 + (l & 15);
                b[fc] = *reinterpret_cast<const bf16x8*>((char*)sB + c * 128 + ((gk ^ (c & 7)) << 4));
            }
#pragma unroll
            for (int fr = 0; fr < 2; ++fr)
#pragma unroll
                for (int fc = 0; fc < 4; ++fc)
                    acc[fr][fc] = __builtin_amdgcn_mfma_f32_16x16x32_bf16(
                        a[fr], b[fc], acc[fr][fc], 0, 0, 0);
        }
    }
#pragma unroll
    for (int fr = 0; fr < 2; ++fr) {
#pragma unroll
        for (int r = 0; r < 4; ++r) {
            int grow = row0 + w * 32 + fr * 16 + (l >> 4) * 4 + r;
            if (grow >= NN) continue;
            float di = dinv[grow];
#pragma unroll
            for (int fc = 0; fc < 4; ++fc) {
                int col = fc * 16 + (l & 15);
                h1s[(size_t)grow * HID + col] = f2bf(acc[fr][fc][r] * di);
            }
        }
    }
}

// ---------------- aggA: edge-centric layer-1 aggregation into LDS tile ----------------
// acc[dl][ch] += h1s[src][ch] per staged entry; epilogue: x = bf16(relu((acc+self)*dinv + b1))
#define A1T 512
__global__ __launch_bounds__(A1T) void k_aggA(
    const unsigned* __restrict__ gcur, const unsigned* __restrict__ staged,
    const unsigned short* __restrict__ h1s, const float* __restrict__ dinv,
    const float* __restrict__ b1, unsigned short* __restrict__ x) {
    extern __shared__ float acc[];            // 256*65 floats = 66,560 B
    const int t = threadIdx.x;
    const int b = blockIdx.x;
    for (int i = t; i < 256 * 65; i += A1T) acc[i] = 0.f;
    __syncthreads();
    unsigned n = gcur[(size_t)b * CPAD];
    if (n > BCAP2) n = BCAP2;
    const unsigned base = (unsigned)b * BCAP2;
    const int wv = t >> 6;       // wave 0..7
    const int l = t & 63;
    const int g = l >> 4;        // entry-in-quad 0..3
    const int c4 = l & 15;       // channel quad 0..15
    for (unsigned it = wv * 4 + g; it < n; it += 32) {
        unsigned p = staged[base + it];          // 16-lane broadcast
        int src = (int)(p & 0x1FFFFu);
        int dl = (int)(p >> 17);
        uint2 v = *reinterpret_cast<const uint2*>(&h1s[(size_t)src * HID + c4 * 4]);
        float* a = &acc[dl * 65 + c4 * 4];       // bank = (dl + ch) % 32, conflict-spread
        atomicAdd(&a[0], asf(v.x << 16));
        atomicAdd(&a[1], asf(v.x & 0xFFFF0000u));
        atomicAdd(&a[2], asf(v.y << 16));
        atomicAdd(&a[3], asf(v.y & 0xFFFF0000u));
    }
    __syncthreads();
    const int node0 = b << 8;
    for (int i = t; i < 256 * 8; i += A1T) {     // 8 ch per thread-step
        int dl = i >> 3, c8 = (i & 7) * 8;
        int node = node0 + dl;
        if (node >= NN) continue;
        float di = dinv[node];
        const unsigned short* hs = &h1s[(size_t)node * HID + c8];
        unsigned short pv[8];
#pragma unroll
        for (int j = 0; j < 8; ++j) {
            float v = acc[dl * 65 + c8 + j] + bf2f(hs[j]);     // + self (prefolded)
            pv[j] = f2bf(fmaxf(fmaf(v, di, b1[c8 + j]), 0.f));
        }
        *reinterpret_cast<uint4*>(&x[(size_t)node * HID + c8]) = *reinterpret_cast<uint4*>(pv);
    }
}

// ---------------- layer 2 GEMM: h2s = bf16( (x @ W2) * dinv ), x bf16 ----------------
__global__ __launch_bounds__(256) void k_gemm2(
    const unsigned short* __restrict__ x, const float* __restrict__ W2,
    const float* __restrict__ dinv, unsigned short* __restrict__ h2s) {
    __shared__ float sW[HID][NC];
    const int t = threadIdx.x;
#pragma unroll
    for (int i = 0; i < 4; ++i) {
        int q = t + i * 256;
        sW[q >> 4][q & 15] = W2[q];
    }
    __syncthreads();
    int i = blockIdx.x * blockDim.x + t;
    if (i >= NN) return;

    float acc[NC];
#pragma unroll
    for (int j = 0; j < NC; ++j) acc[j] = 0.f;
    const unsigned short* xr = &x[(size_t)i * HID];
#pragma unroll
    for (int k8 = 0; k8 < 8; ++k8) {
        uint4 u = *reinterpret_cast<const uint4*>(&xr[k8 * 8]);
        float f[8] = {asf(u.x << 16), asf(u.x & 0xFFFF0000u),
                      asf(u.y << 16), asf(u.y & 0xFFFF0000u),
                      asf(u.z << 16), asf(u.z & 0xFFFF0000u),
                      asf(u.w << 16), asf(u.w & 0xFFFF0000u)};
#pragma unroll
        for (int m = 0; m < 8; ++m)
#pragma unroll
            for (int j = 0; j < NC; ++j)
                acc[j] = fmaf(f[m], sW[k8 * 8 + m][j], acc[j]);
    }
    float di = dinv[i];
    unsigned short hv[NC];
#pragma unroll
    for (int j = 0; j < NC; ++j) hv[j] = f2bf(acc[j] * di);
    *reinterpret_cast<uint4*>(&h2s[(size_t)i * NC])     = *reinterpret_cast<uint4*>(hv);
    *reinterpret_cast<uint4*>(&h2s[(size_t)i * NC + 8]) = *reinterpret_cast<uint4*>(hv + 8);
}

// ---------------- aggB: edge-centric layer-2 aggregation into LDS tile ----------------
__global__ __launch_bounds__(256) void k_aggB(
    const unsigned* __restrict__ gcur, const unsigned* __restrict__ staged,
    const unsigned short* __restrict__ h2s, const float* __restrict__ dinv,
    const float* __restrict__ b2, float* __restrict__ out) {
    __shared__ float acc[256 * 17];     // 17.4 KB
    const int t = threadIdx.x;
    const int b = blockIdx.x;
    for (int i = t; i < 256 * 17; i += 256) acc[i] = 0.f;
    __syncthreads();
    unsigned n = gcur[(size_t)b * CPAD];
    if (n > BCAP2) n = BCAP2;
    const unsigned base = (unsigned)b * BCAP2;
    const int wv = t >> 6;       // wave 0..3
    const int l = t & 63;
    const int g = l >> 2;        // entry 0..15 within wave step
    const int c4 = l & 3;        // channel quad 0..3
    for (unsigned it = wv * 16 + g; it < n; it += 64) {
        unsigned p = staged[base + it];
        int src = (int)(p & 0x1FFFFu);
        int dl = (int)(p >> 17);
        uint2 v = *reinterpret_cast<const uint2*>(&h2s[(size_t)src * NC + c4 * 4]);
        float* a = &acc[dl * 17 + c4 * 4];
        atomicAdd(&a[0], asf(v.x << 16));
        atomicAdd(&a[1], asf(v.x & 0xFFFF0000u));
        atomicAdd(&a[2], asf(v.y << 16));
        atomicAdd(&a[3], asf(v.y & 0xFFFF0000u));
    }
    __syncthreads();
    const int node0 = b << 8;
    for (int i = t; i < 256 * 4; i += 256) {
        int dl = i >> 2, c4o = (i & 3) * 4;
        int node = node0 + dl;
        if (node >= NN) continue;
        float di = dinv[node];
        const unsigned short* hs = &h2s[(size_t)node * NC + c4o];
        float4 r;
        r.x = fmaf(acc[dl * 17 + c4o + 0] + bf2f(hs[0]), di, b2[c4o + 0]);
        r.y = fmaf(acc[dl * 17 + c4o + 1] + bf2f(hs[1]), di, b2[c4o + 1]);
        r.z = fmaf(acc[dl * 17 + c4o + 2] + bf2f(hs[2]), di, b2[c4o + 2]);
        r.w = fmaf(acc[dl * 17 + c4o + 3] + bf2f(hs[3]), di, b2[c4o + 3]);
        *reinterpret_cast<float4*>(&out[(size_t)node * NC + c4o]) = r;
    }
}

extern "C" void kernel_launch(void* const* d_in, const int* in_sizes, int n_in,
                              void* d_out, int out_size, void* d_ws, size_t ws_size,
                              hipStream_t stream) {
    const float* features = (const float*)d_in[0];
    const int*   edges    = (const int*)d_in[1];
    const float* W1       = (const float*)d_in[2];
    const float* b1       = (const float*)d_in[3];
    const float* W2       = (const float*)d_in[4];
    const float* b2       = (const float*)d_in[5];
    float* out = (float*)d_out;

    const int* erow = edges;
    const int* ecol = edges + EE;

    char* ws = (char*)d_ws;
    size_t o = 0;
    auto alloc = [&](size_t bytes) { size_t p = o; o = (o + bytes + 255) & ~255ULL; return p; };
    unsigned*       gcur  = (unsigned*)      (ws + alloc((size_t)KB2 * CPAD * 4));
    float*          dinv  = (float*)         (ws + alloc((size_t)NN * 4));
    unsigned*       staged= (unsigned*)      (ws + alloc((size_t)KB2 * BCAP2 * 4));   // 7.2 MB
    unsigned short* W1t   = (unsigned short*)(ws + alloc((size_t)HID * FIN * 2));
    unsigned short* h1s   = (unsigned short*)(ws + alloc((size_t)NN * HID * 2));      // bf16, dinv-prefolded
    unsigned short* x     = (unsigned short*)(ws + alloc((size_t)NN * HID * 2));      // bf16
    unsigned short* h2s   = (unsigned short*)(ws + alloc((size_t)NN * NC * 2));       // bf16, dinv-prefolded

    // ---- 7-dispatch pipeline, no ELL intermediate ----
    k_init <<<128, 256, 0, stream>>>(W1, W1t, gcur);
    k_bin  <<<NBIN, 256, 0, stream>>>(erow, ecol, gcur, staged);
    k_cnt  <<<KB2, 256, 0, stream>>>(gcur, staged, dinv);
    k_gemm1<<<(NN + BM - 1) / BM, 256, 0, stream>>>(features, W1t, dinv, h1s);
    k_aggA <<<KB2, A1T, 256 * 65 * sizeof(float), stream>>>(gcur, staged, h1s, dinv, b1, x);
    k_gemm2<<<(NN + 255) / 256, 256, 0, stream>>>(x, W2, dinv, h2s);
    k_aggB <<<KB2, 256, 0, stream>>>(gcur, staged, h2s, dinv, b2, out);
}

// Round 13
// 185.818 us; speedup vs baseline: 5.1150x; 5.1150x over previous
//
#include <hip/hip_runtime.h>

#define NN 100000
#define EE 1600000
#define FIN 512
#define HID 64
#define NC 16
#define ELLW 64          // max in-degree capacity (Poisson(16), max ~42)
#define CPAD 16          // one counter per 64B line (bucket cursors)

#define KB_ 196          // buckets: 512 dst nodes each, ceil(100000/512)
#define BCAP 10240       // staged entries per bucket (mean 8192)
#define S1E 2048         // edges per S1 block

typedef __attribute__((ext_vector_type(8))) short bf16x8;
typedef __attribute__((ext_vector_type(4))) float f32x4;

__device__ __forceinline__ unsigned short f2bf(float f) {
    union { float f; unsigned u; } v; v.f = f;
    unsigned r = v.u + 0x7FFFu + ((v.u >> 16) & 1u);   // RNE
    return (unsigned short)(r >> 16);
}
__device__ __forceinline__ float asf(unsigned u) {
    union { unsigned u; float f; } v; v.u = u; return v.f;
}

// ---------------- init: zero bucket cursors + W1 -> bf16 transposed [col][k] ----------------
__global__ void k_init(const float* __restrict__ W1, unsigned short* __restrict__ W1t,
                       unsigned* __restrict__ gcur) {
    int id = blockIdx.x * blockDim.x + threadIdx.x;
    if (id < KB_ * CPAD) gcur[id] = 0u;
    if (id < HID * FIN) {
        int c = id >> 9;      // col 0..63
        int k = id & 511;
        W1t[id] = f2bf(W1[(size_t)k * HID + c]);
    }
}

// ---------------- S1: bin edges by dst bucket, LDS-reordered coalesced output ----------------
__global__ __launch_bounds__(256) void k_bin(
    const int* __restrict__ erow, const int* __restrict__ ecol,
    unsigned* __restrict__ gcur, unsigned* __restrict__ staged) {
    __shared__ unsigned hist[256];
    __shared__ unsigned scanb[256];
    __shared__ unsigned cur[256];
    __shared__ unsigned sbase[256];
    __shared__ unsigned pk[S1E];
    __shared__ unsigned ga[S1E];
    const int t = threadIdx.x;
    const int e0 = blockIdx.x * S1E;

    hist[t] = 0;
    cur[t] = 0;
    __syncthreads();

    unsigned pkd[8];
    int bs[8];
#pragma unroll
    for (int i = 0; i < 8; ++i) {
        int e = e0 + i * 256 + t;
        if (e < EE) {
            int c = ecol[e];
            int src = erow[e];
            int b = c >> 9;
            bs[i] = b;
            pkd[i] = (unsigned)src | ((unsigned)(c & 511) << 17);
            atomicAdd(&hist[b], 1u);
        } else {
            bs[i] = -1;
        }
    }
    __syncthreads();
    // inclusive scan of hist -> scanb
    scanb[t] = hist[t];
    __syncthreads();
    for (int d = 1; d < 256; d <<= 1) {
        unsigned add = (t >= d) ? scanb[t - d] : 0u;
        __syncthreads();
        scanb[t] += add;
        __syncthreads();
    }
    // reserve global range per bucket
    if (t < KB_ && hist[t] > 0) sbase[t] = atomicAdd(&gcur[(size_t)t * CPAD], hist[t]);
    __syncthreads();
    // place entries grouped by bucket in LDS; record global dest addr
#pragma unroll
    for (int i = 0; i < 8; ++i) {
        int b = bs[i];
        if (b >= 0) {
            unsigned ls = atomicAdd(&cur[b], 1u);
            unsigned pos = scanb[b] - hist[b] + ls;      // exclusive + local slot
            unsigned gp = sbase[b] + ls;
            pk[pos] = pkd[i];
            ga[pos] = (gp < BCAP) ? ((unsigned)b * BCAP + gp) : 0xFFFFFFFFu;
        }
    }
    __syncthreads();
    unsigned tot = scanb[255];
#pragma unroll
    for (int i = 0; i < 8; ++i) {
        unsigned idx = i * 256 + t;
        if (idx < tot && ga[idx] != 0xFFFFFFFFu) staged[ga[idx]] = pk[idx];
    }
}

// ---------------- S2: per-bucket scatter into ELL, LDS slot counters; emits cnt+dinv ----------------
__global__ __launch_bounds__(256) void k_scat2(
    const unsigned* __restrict__ gcur, const unsigned* __restrict__ staged,
    int* __restrict__ ell, unsigned* __restrict__ cnt, float* __restrict__ dinv) {
    __shared__ unsigned lcnt[512];
    const int t = threadIdx.x;
    const int b = blockIdx.x;
    lcnt[t] = 0; lcnt[t + 256] = 0;
    __syncthreads();
    unsigned n = gcur[(size_t)b * CPAD];
    if (n > BCAP) n = BCAP;
    const unsigned base = (unsigned)b * BCAP;
    const int node0 = b << 9;
    for (unsigned idx = t; idx < n; idx += 256) {
        unsigned p = staged[base + idx];
        int src = (int)(p & 0x1FFFFu);
        int dl = (int)(p >> 17);
        unsigned slot = atomicAdd(&lcnt[dl], 1u);
        if (slot < ELLW) ell[(size_t)(node0 + dl) * ELLW + slot] = src;
    }
    __syncthreads();
#pragma unroll
    for (int i = 0; i < 2; ++i) {
        int dl = i * 256 + t;
        int node = node0 + dl;
        if (node < NN) {
            unsigned c = lcnt[dl];
            cnt[node] = c;
            dinv[node] = 1.0f / sqrtf((float)(c + 1u));   // +1 self-loop
        }
    }
}

// ---------------- layer 1 GEMM via MFMA: h1s = bf16( (A@W1) * dinv ) ----------------
#define BM 128
#define BK 64

__global__ __launch_bounds__(256) void k_gemm1(
    const float* __restrict__ A, const unsigned short* __restrict__ W1t,
    const float* __restrict__ dinv, unsigned short* __restrict__ h1s) {
    __shared__ unsigned short sA[BM * BK];   // 16 KB
    __shared__ unsigned short sB[HID * BK];  // 8 KB
    const int t = threadIdx.x;
    const int w = t >> 6;
    const int l = t & 63;
    const int row0 = blockIdx.x * BM;

    f32x4 acc[2][4];
#pragma unroll
    for (int fr = 0; fr < 2; ++fr)
#pragma unroll
        for (int fc = 0; fc < 4; ++fc)
            acc[fr][fc] = (f32x4){0.f, 0.f, 0.f, 0.f};

    for (int kb = 0; kb < FIN; kb += BK) {
        __syncthreads();
#pragma unroll
        for (int i = 0; i < 4; ++i) {
            int idx = i * 256 + t;
            int r = idx >> 3, g = idx & 7;
            float4 v0 = {0.f, 0.f, 0.f, 0.f}, v1 = {0.f, 0.f, 0.f, 0.f};
            if (row0 + r < NN) {
                const float* p = &A[(size_t)(row0 + r) * FIN + kb + g * 8];
                v0 = *reinterpret_cast<const float4*>(p);
                v1 = *reinterpret_cast<const float4*>(p + 4);
            }
            unsigned short tmp[8] = {f2bf(v0.x), f2bf(v0.y), f2bf(v0.z), f2bf(v0.w),
                                     f2bf(v1.x), f2bf(v1.y), f2bf(v1.z), f2bf(v1.w)};
            *reinterpret_cast<uint4*>((char*)sA + r * 128 + ((g ^ (r & 7)) << 4)) =
                *reinterpret_cast<uint4*>(tmp);
        }
#pragma unroll
        for (int i = 0; i < 2; ++i) {
            int idx = i * 256 + t;
            int c = idx >> 3, g = idx & 7;
            uint4 v = *reinterpret_cast<const uint4*>(&W1t[(size_t)c * FIN + kb + g * 8]);
            *reinterpret_cast<uint4*>((char*)sB + c * 128 + ((g ^ (c & 7)) << 4)) = v;
        }
        __syncthreads();
#pragma unroll
        for (int ks = 0; ks < 2; ++ks) {
            const int gk = ks * 4 + (l >> 4);
            bf16x8 a[2], b[4];
#pragma unroll
            for (int fr = 0; fr < 2; ++fr) {
                int r = w * 32 + fr * 16 + (l & 15);
                a[fr] = *reinterpret_cast<const bf16x8*>((char*)sA + r * 128 + ((gk ^ (r & 7)) << 4));
            }
#pragma unroll
            for (int fc = 0; fc < 4; ++fc) {
                int c = fc * 16 + (l & 15);
                b[fc] = *reinterpret_cast<const bf16x8*>((char*)sB + c * 128 + ((gk ^ (c & 7)) << 4));
            }
#pragma unroll
            for (int fr = 0; fr < 2; ++fr)
#pragma unroll
                for (int fc = 0; fc < 4; ++fc)
                    acc[fr][fc] = __builtin_amdgcn_mfma_f32_16x16x32_bf16(
                        a[fr], b[fc], acc[fr][fc], 0, 0, 0);
        }
    }
#pragma unroll
    for (int fr = 0; fr < 2; ++fr) {
#pragma unroll
        for (int r = 0; r < 4; ++r) {
            int grow = row0 + w * 32 + fr * 16 + (l >> 4) * 4 + r;
            if (grow >= NN) continue;
            float di = dinv[grow];
#pragma unroll
            for (int fc = 0; fc < 4; ++fc) {
                int col = fc * 16 + (l & 15);
                h1s[(size_t)grow * HID + col] = f2bf(acc[fr][fc][r] * di);
            }
        }
    }
}

// ---------------- layer 1 aggregation: wave/node, 8 edges/iter, 8ch/lane ----------------
__global__ __launch_bounds__(256) void k_agg1(
    const unsigned* __restrict__ cnt, const int* __restrict__ ell,
    const unsigned short* __restrict__ h1s, const float* __restrict__ dinv,
    const float* __restrict__ b1, unsigned short* __restrict__ x) {
    int wid = (blockIdx.x * blockDim.x + threadIdx.x) >> 6;
    if (wid >= NN) return;
    const int l = threadIdx.x & 63;
    const int g = l >> 3;      // edge subgroup 0..7
    const int q = l & 7;       // channel octet
    const int total = (int)cnt[wid] + 1;   // +1 virtual self edge (e==0)
    const int base = wid * ELLW;

    float a0 = 0.f, a1 = 0.f, a2 = 0.f, a3 = 0.f;
    float a4 = 0.f, a5 = 0.f, a6 = 0.f, a7 = 0.f;
    for (int s = 0; s < total; s += 8) {
        int e = s + g;
        int ee = min(e, total - 1);
        int src = (ee == 0) ? wid : ell[base + ee - 1];
        uint4 u = *reinterpret_cast<const uint4*>(&h1s[(size_t)src * HID + q * 8]);
        float m = (e < total) ? 1.f : 0.f;
        a0 = fmaf(m, asf(u.x << 16), a0);
        a1 = fmaf(m, asf(u.x & 0xFFFF0000u), a1);
        a2 = fmaf(m, asf(u.y << 16), a2);
        a3 = fmaf(m, asf(u.y & 0xFFFF0000u), a3);
        a4 = fmaf(m, asf(u.z << 16), a4);
        a5 = fmaf(m, asf(u.z & 0xFFFF0000u), a5);
        a6 = fmaf(m, asf(u.w << 16), a6);
        a7 = fmaf(m, asf(u.w & 0xFFFF0000u), a7);
    }
#pragma unroll
    for (int d = 8; d <= 32; d <<= 1) {
        a0 += __shfl_xor(a0, d); a1 += __shfl_xor(a1, d);
        a2 += __shfl_xor(a2, d); a3 += __shfl_xor(a3, d);
        a4 += __shfl_xor(a4, d); a5 += __shfl_xor(a5, d);
        a6 += __shfl_xor(a6, d); a7 += __shfl_xor(a7, d);
    }
    if (g == 0) {
        float di = dinv[wid];
        float4 bA = *reinterpret_cast<const float4*>(&b1[q * 8]);
        float4 bB = *reinterpret_cast<const float4*>(&b1[q * 8 + 4]);
        float r0 = fmaxf(fmaf(a0, di, bA.x), 0.f);
        float r1 = fmaxf(fmaf(a1, di, bA.y), 0.f);
        float r2 = fmaxf(fmaf(a2, di, bA.z), 0.f);
        float r3 = fmaxf(fmaf(a3, di, bA.w), 0.f);
        float r4 = fmaxf(fmaf(a4, di, bB.x), 0.f);
        float r5 = fmaxf(fmaf(a5, di, bB.y), 0.f);
        float r6 = fmaxf(fmaf(a6, di, bB.z), 0.f);
        float r7 = fmaxf(fmaf(a7, di, bB.w), 0.f);
        uint4 pv;
        pv.x = (unsigned)f2bf(r0) | ((unsigned)f2bf(r1) << 16);
        pv.y = (unsigned)f2bf(r2) | ((unsigned)f2bf(r3) << 16);
        pv.z = (unsigned)f2bf(r4) | ((unsigned)f2bf(r5) << 16);
        pv.w = (unsigned)f2bf(r6) | ((unsigned)f2bf(r7) << 16);
        *reinterpret_cast<uint4*>(&x[(size_t)wid * HID + q * 8]) = pv;
    }
}

// ---------------- layer 2 GEMM: h2s = bf16( (x @ W2) * dinv ), x bf16 ----------------
__global__ __launch_bounds__(256) void k_gemm2(
    const unsigned short* __restrict__ x, const float* __restrict__ W2,
    const float* __restrict__ dinv, unsigned short* __restrict__ h2s) {
    __shared__ float sW[HID][NC];   // 4 KB
    const int t = threadIdx.x;
#pragma unroll
    for (int i = 0; i < 4; ++i) {
        int q = t + i * 256;
        sW[q >> 4][q & 15] = W2[q];
    }
    __syncthreads();
    int i = blockIdx.x * blockDim.x + t;
    if (i >= NN) return;

    float acc[NC];
#pragma unroll
    for (int j = 0; j < NC; ++j) acc[j] = 0.f;
    const unsigned short* xr = &x[(size_t)i * HID];
#pragma unroll
    for (int k8 = 0; k8 < 8; ++k8) {
        uint4 u = *reinterpret_cast<const uint4*>(&xr[k8 * 8]);
        float f[8] = {asf(u.x << 16), asf(u.x & 0xFFFF0000u),
                      asf(u.y << 16), asf(u.y & 0xFFFF0000u),
                      asf(u.z << 16), asf(u.z & 0xFFFF0000u),
                      asf(u.w << 16), asf(u.w & 0xFFFF0000u)};
#pragma unroll
        for (int m = 0; m < 8; ++m)
#pragma unroll
            for (int j = 0; j < NC; ++j)
                acc[j] = fmaf(f[m], sW[k8 * 8 + m][j], acc[j]);
    }
    float di = dinv[i];
    unsigned short hv[NC];
#pragma unroll
    for (int j = 0; j < NC; ++j) hv[j] = f2bf(acc[j] * di);
    *reinterpret_cast<uint4*>(&h2s[(size_t)i * NC])     = *reinterpret_cast<uint4*>(hv);
    *reinterpret_cast<uint4*>(&h2s[(size_t)i * NC + 8]) = *reinterpret_cast<uint4*>(hv + 8);
}

// ---------------- layer 2 aggregation: wave/node, 32 edges/iter, 8ch/lane ----------------
__global__ __launch_bounds__(256) void k_agg2(
    const unsigned* __restrict__ cnt, const int* __restrict__ ell,
    const unsigned short* __restrict__ h2s, const float* __restrict__ dinv,
    const float* __restrict__ b2, float* __restrict__ out) {
    int wid = (blockIdx.x * blockDim.x + threadIdx.x) >> 6;
    if (wid >= NN) return;
    const int l = threadIdx.x & 63;
    const int g = l >> 1;      // edge subgroup 0..31
    const int q = l & 1;       // channel octet
    const int total = (int)cnt[wid] + 1;   // +1 self
    const int base = wid * ELLW;

    float a0 = 0.f, a1 = 0.f, a2 = 0.f, a3 = 0.f;
    float a4 = 0.f, a5 = 0.f, a6 = 0.f, a7 = 0.f;
    for (int s = 0; s < total; s += 32) {
        int e = s + g;
        int ee = min(e, total - 1);
        int src = (ee == 0) ? wid : ell[base + ee - 1];
        uint4 u = *reinterpret_cast<const uint4*>(&h2s[(size_t)src * NC + q * 8]);
        float m = (e < total) ? 1.f : 0.f;
        a0 = fmaf(m, asf(u.x << 16), a0);
        a1 = fmaf(m, asf(u.x & 0xFFFF0000u), a1);
        a2 = fmaf(m, asf(u.y << 16), a2);
        a3 = fmaf(m, asf(u.y & 0xFFFF0000u), a3);
        a4 = fmaf(m, asf(u.z << 16), a4);
        a5 = fmaf(m, asf(u.z & 0xFFFF0000u), a5);
        a6 = fmaf(m, asf(u.w << 16), a6);
        a7 = fmaf(m, asf(u.w & 0xFFFF0000u), a7);
    }
#pragma unroll
    for (int d = 2; d <= 32; d <<= 1) {
        a0 += __shfl_xor(a0, d); a1 += __shfl_xor(a1, d);
        a2 += __shfl_xor(a2, d); a3 += __shfl_xor(a3, d);
        a4 += __shfl_xor(a4, d); a5 += __shfl_xor(a5, d);
        a6 += __shfl_xor(a6, d); a7 += __shfl_xor(a7, d);
    }
    if (g == 0) {   // lanes 0,1
        float di = dinv[wid];
        float4 bA = *reinterpret_cast<const float4*>(&b2[q * 8]);
        float4 bB = *reinterpret_cast<const float4*>(&b2[q * 8 + 4]);
        float4 w0, w1;
        w0.x = fmaf(a0, di, bA.x); w0.y = fmaf(a1, di, bA.y);
        w0.z = fmaf(a2, di, bA.z); w0.w = fmaf(a3, di, bA.w);
        w1.x = fmaf(a4, di, bB.x); w1.y = fmaf(a5, di, bB.y);
        w1.z = fmaf(a6, di, bB.z); w1.w = fmaf(a7, di, bB.w);
        *reinterpret_cast<float4*>(&out[(size_t)wid * NC + q * 8])     = w0;
        *reinterpret_cast<float4*>(&out[(size_t)wid * NC + q * 8 + 4]) = w1;
    }
}

extern "C" void kernel_launch(void* const* d_in, const int* in_sizes, int n_in,
                              void* d_out, int out_size, void* d_ws, size_t ws_size,
                              hipStream_t stream) {
    const float* features = (const float*)d_in[0];
    const int*   edges    = (const int*)d_in[1];   // [2, E] int32
    const float* W1       = (const float*)d_in[2];
    const float* b1       = (const float*)d_in[3];
    const float* W2       = (const float*)d_in[4];
    const float* b2       = (const float*)d_in[5];
    float* out = (float*)d_out;

    const int* erow = edges;        // sources
    const int* ecol = edges + EE;   // targets

    // ---- workspace layout ----
    char* ws = (char*)d_ws;
    size_t o = 0;
    auto alloc = [&](size_t bytes) { size_t p = o; o = (o + bytes + 255) & ~255ULL; return p; };
    unsigned*       gcur  = (unsigned*)      (ws + alloc((size_t)KB_ * CPAD * 4));       // 12.5 KB
    unsigned*       cnt   = (unsigned*)      (ws + alloc((size_t)NN * 4));
    float*          dinv  = (float*)         (ws + alloc((size_t)NN * 4));
    unsigned*       staged= (unsigned*)      (ws + alloc((size_t)KB_ * BCAP * 4));       // 8.0 MB
    unsigned short* W1t   = (unsigned short*)(ws + alloc((size_t)HID * FIN * 2));
    int*            ell   = (int*)           (ws + alloc((size_t)(KB_ << 9) * ELLW * 4)); // 25.7 MB
    unsigned short* h1s   = (unsigned short*)(ws + alloc((size_t)NN * HID * 2));          // bf16
    unsigned short* x     = (unsigned short*)(ws + alloc((size_t)NN * HID * 2));          // bf16
    unsigned short* h2s   = (unsigned short*)(ws + alloc((size_t)NN * NC * 2));           // bf16

    // ---- 7-dispatch pipeline (R6 structure, init merged) ----
    k_init <<<128, 256, 0, stream>>>(W1, W1t, gcur);
    k_bin  <<<(EE + S1E - 1) / S1E, 256, 0, stream>>>(erow, ecol, gcur, staged);
    k_scat2<<<KB_, 256, 0, stream>>>(gcur, staged, ell, cnt, dinv);
    k_gemm1<<<(NN + BM - 1) / BM, 256, 0, stream>>>(features, W1t, dinv, h1s);
    k_agg1 <<<NN / 4, 256, 0, stream>>>(cnt, ell, h1s, dinv, b1, x);
    k_gemm2<<<(NN + 255) / 256, 256, 0, stream>>>(x, W2, dinv, h2s);
    k_agg2 <<<NN / 4, 256, 0, stream>>>(cnt, ell, h2s, dinv, b2, out);
}